// Round 1
// baseline (14.870 us; speedup 1.0000x reference)
//
#include <hip/hip_runtime.h>

// velocity[b,i,j,:] = sum_v tau_v/(2pi) * (1-exp(-sq/sig^2))/sq * (d1, -d0)
// where d0 = p.y - loc.y, d1 = p.x - loc.x  (p stored as (y,x) like loc)

constexpr int NV = 256;          // vortices per batch
constexpr int PPB = 16384;       // points per batch (128*128)
constexpr float INV_2PI = 0.15915494309189535f;

__global__ __launch_bounds__(256) void vortex_vel_kernel(
    const float* __restrict__ vf,    // (4, 256, 4): y,x,tau,sig
    const float* __restrict__ pts,   // (4, 128, 128, 2)
    float* __restrict__ out)         // (4, 128, 128, 2)
{
    const int b = blockIdx.x >> 6;          // 64 blocks per batch
    const int pbase = (blockIdx.x & 63) << 8;
    const int t = threadIdx.x;

    __shared__ float sy[NV], sx[NV], st[NV], sis[NV];

    // Stage + pre-transform vortex features: one vortex per thread.
    {
        const float4 v = reinterpret_cast<const float4*>(vf)[b * NV + t];
        sy[t]  = v.x;
        sx[t]  = v.y;
        st[t]  = v.z * INV_2PI;            // tau / (2*pi)
        sis[t] = 1.0f / (v.w * v.w);       // 1 / sigma^2
    }
    __syncthreads();

    const int pidx = b * PPB + pbase + t;
    const float2 p = reinterpret_cast<const float2*>(pts)[pidx];

    float v0 = 0.0f, v1 = 0.0f;
    #pragma unroll 8
    for (int k = 0; k < NV; ++k) {
        const float d0 = p.x - sy[k];
        const float d1 = p.y - sx[k];
        const float sq = d0 * d0 + d1 * d1;
        // (1 - exp(-sq/sig^2)) / sq * tau/(2pi)
        const float e    = __expf(-sq * sis[k]);
        const float fall = st[k] * (1.0f - e) * __builtin_amdgcn_rcpf(sq);
        v0 = fmaf(fall, d1, v0);
        v1 = fmaf(-fall, d0, v1);
    }

    reinterpret_cast<float2*>(out)[pidx] = make_float2(v0, v1);
}

extern "C" void kernel_launch(void* const* d_in, const int* in_sizes, int n_in,
                              void* d_out, int out_size, void* d_ws, size_t ws_size,
                              hipStream_t stream) {
    const float* vf  = (const float*)d_in[0];   // (4,256,4)
    const float* pts = (const float*)d_in[1];   // (4,128,128,2)
    float* out = (float*)d_out;                 // (4,128,128,2)

    dim3 grid(256);   // 4 batches * 64 blocks
    dim3 block(256);
    vortex_vel_kernel<<<grid, block, 0, stream>>>(vf, pts, out);
}

// Round 2
// 13.479 us; speedup vs baseline: 1.1032x; 1.1032x over previous
//
#include <hip/hip_runtime.h>

// velocity[b,p,:] = 1/(2pi) * sum_v tau_v * (1-exp(-sq/sig^2))/sq * (d1, -d0)
// d = p - loc;  vf = (4,256,4) [y,x,tau,sig];  pts/out = (4,16384,2)

constexpr int NV = 256;          // vortices per batch
constexpr int PPB = 16384;       // points per batch
constexpr float INV_2PI = 0.15915494309189535f;

__global__ __launch_bounds__(256) void vortex_vel_kernel(
    const float4* __restrict__ vf,   // (4,256) of {y,x,tau,sig}
    const float2* __restrict__ pts,  // (4*16384)
    float* __restrict__ out)         // (4*16384*2)
{
    const int b     = blockIdx.x >> 8;           // 256 blocks per batch
    const int pbase = (blockIdx.x & 255) << 6;   // 64 points per block
    const int t     = threadIdx.x;
    const int lane  = t & 63;
    // wave id = vortex chunk; readfirstlane forces it scalar so the vortex
    // loads below have a provably uniform address -> s_load_dwordx4 (K$),
    // no LDS / no per-lane VMEM in the hot loop.
    const int chunk = __builtin_amdgcn_readfirstlane(t >> 6);

    const float2 p = pts[b * PPB + pbase + lane];
    const float4* vfc = vf + b * NV + chunk * 64;

    float v0 = 0.0f, v1 = 0.0f;
    #pragma unroll 8
    for (int k = 0; k < 64; ++k) {
        const float4 v = vfc[k];                 // y,x,tau,sig (wave-uniform)
        const float d0 = p.x - v.x;
        const float d1 = p.y - v.y;
        const float sq = fmaf(d0, d0, d1 * d1);
        const float sig2 = v.w * v.w;
        const float e = __expf(-sq * __builtin_amdgcn_rcpf(sig2));
        const float r = __builtin_amdgcn_rcpf(sq);
        const float w = fmaf(-e, r, r) * v.z;    // tau * (1-e) / sq
        v0 = fmaf(w, d1, v0);
        v1 = fmaf(-w, d0, v1);
    }

    // Reduce the 4 vortex-chunk partials per point. red[w][pt][c] word index
    // for the read below is w*128 + t: stride-1 across lanes, conflict-free.
    __shared__ float red[4][64][2];
    red[chunk][lane][0] = v0;
    red[chunk][lane][1] = v1;
    __syncthreads();

    if (t < 128) {
        const int pt = t >> 1, c = t & 1;
        const float s = red[0][pt][c] + red[1][pt][c]
                      + red[2][pt][c] + red[3][pt][c];
        out[(b * PPB + pbase) * 2 + t] = s * INV_2PI;
    }
}

extern "C" void kernel_launch(void* const* d_in, const int* in_sizes, int n_in,
                              void* d_out, int out_size, void* d_ws, size_t ws_size,
                              hipStream_t stream) {
    const float4* vf  = (const float4*)d_in[0];  // (4,256,4)
    const float2* pts = (const float2*)d_in[1];  // (4,128,128,2)
    float* out = (float*)d_out;

    dim3 grid(1024);   // 4 batches * 256 point-blocks (64 pts each, 4 chunks)
    dim3 block(256);
    vortex_vel_kernel<<<grid, block, 0, stream>>>(vf, pts, out);
}